// Round 3
// baseline (123.186 us; speedup 1.0000x reference)
//
#include <hip/hip_runtime.h>
#include <hip/hip_fp16.h>

// bias = (1/nnz) * sum_e vals[e] * dot(x[rows[e]], x[cols[e]])
// N_FEAT = 128 -> fp16 row = 256B = 2 L2 lines.
//
// Round-3 strategy: the binding resource is the random L2-line fill rate
// (~27 G lines/s measured, constant across rounds 1-2). Raise hit rate on
// the col side via XCD affinity: block b serves col-octant (b&7); its col
// gathers then live in a 3.2MB slice resident in that XCD's 4MB L2.
// Edges are scanned (sequentially, nontemporal) by every octant and
// compacted deterministically (wave-ordered prefix sum) before gathering.

struct h4pack { __half2 a, b; };

__global__ __launch_bounds__(256) void convert_f2h_kernel(
    const float* __restrict__ x, h4pack* __restrict__ xh, int n4)
{
    const float4* __restrict__ x4 = reinterpret_cast<const float4*>(x);
    int i = blockIdx.x * blockDim.x + threadIdx.x;
    const int stride = gridDim.x * blockDim.x;
    for (; i < n4; i += stride) {
        float4 f = x4[i];
        h4pack p;
        p.a = __floats2half2_rn(f.x, f.y);
        p.b = __floats2half2_rn(f.z, f.w);
        xh[i] = p;
    }
}

__global__ __launch_bounds__(256) void edge_dot_oct_kernel(
    const __half* __restrict__ xh,
    const int* __restrict__ rows,
    const int* __restrict__ cols,
    const float* __restrict__ vals,
    float* __restrict__ partials,
    int nnz, int nodes_per_oct)
{
    const float4* __restrict__ xh4 = reinterpret_cast<const float4*>(xh);

    const int oct  = blockIdx.x & 7;         // XCD affinity (round-robin dispatch)
    const int obid = blockIdx.x >> 3;        // block index within octant
    const int nb   = gridDim.x >> 3;         // blocks per octant
    const int lo   = oct * nodes_per_oct;
    const int hi   = lo + nodes_per_oct;

    const int tid  = threadIdx.x;
    const int wid  = tid >> 6;
    const int lane = tid & 63;

    __shared__ int s_list[256];   // packed (col<<8)|tid, col<2^17 fits
    __shared__ int s_cnt[4];
    __shared__ float s_red[4];

    float acc = 0.0f;

    long long base = (long long)obid * 256;
    const long long tile_stride = (long long)nb * 256;

    for (; base < nnz; base += tile_stride) {
        const long long e = base + tid;
        int c = -1;
        if (e < nnz) c = __builtin_nontemporal_load(cols + e);
        const bool m = (c >= lo) && (c < hi);

        const unsigned long long mask = __ballot(m);
        if (lane == 0) s_cnt[wid] = __popcll(mask);
        __syncthreads();

        int wbase = 0;
        #pragma unroll
        for (int w = 0; w < 4; ++w)
            if (w < wid) wbase += s_cnt[w];
        const int total = s_cnt[0] + s_cnt[1] + s_cnt[2] + s_cnt[3];

        if (m) {
            const int pos = wbase +
                __popcll(mask & ((1ull << lane) - 1ull));
            s_list[pos] = (c << 8) | tid;
        }
        __syncthreads();

        // gather phase: 16 groups of 16 lanes, group g does list[g], g+16, ...
        const int g = tid >> 4, sub = tid & 15;
        for (int i = g; i < total; i += 16) {
            const int packed = s_list[i];
            const int cc = packed >> 8;
            const long long ee = base + (packed & 255);
            const int   rr = rows[ee];          // broadcast load (same addr x16)
            const float vv = vals[ee];
            const float4 af = xh4[(size_t)rr * 16 + sub];
            const float4 bf = xh4[(size_t)cc * 16 + sub];
            const __half2* a2 = reinterpret_cast<const __half2*>(&af);
            const __half2* b2 = reinterpret_cast<const __half2*>(&bf);
            float d = 0.0f;
            #pragma unroll
            for (int k = 0; k < 4; ++k) {
                float2 fa = __half22float2(a2[k]);
                float2 fb = __half22float2(b2[k]);
                d += fa.x * fb.x + fa.y * fb.y;
            }
            acc += vv * d;
        }
        __syncthreads();   // protect s_list/s_cnt before next tile
    }

    // block reduction (deterministic)
    #pragma unroll
    for (int mask2 = 1; mask2 < 64; mask2 <<= 1)
        acc += __shfl_xor(acc, mask2);
    if (lane == 0) s_red[wid] = acc;
    __syncthreads();
    if (tid == 0) {
        partials[blockIdx.x] = s_red[0] + s_red[1] + s_red[2] + s_red[3];
    }
}

// fp32 fallback (workspace too small for fp16 shadow copy)
__global__ __launch_bounds__(256) void edge_dot_f_kernel(
    const float* __restrict__ x,
    const int* __restrict__ rows,
    const int* __restrict__ cols,
    const float* __restrict__ vals,
    float* __restrict__ partials,
    int nnz)
{
    const float4* __restrict__ x4 = reinterpret_cast<const float4*>(x);
    const int sub = threadIdx.x & 31;
    const int groupInBlock = threadIdx.x >> 5;
    const int groupsPerBlock = blockDim.x >> 5;
    const long long gstride = (long long)gridDim.x * groupsPerBlock;
    long long e = (long long)blockIdx.x * groupsPerBlock + groupInBlock;

    float acc = 0.0f;
    for (; e < nnz; e += gstride) {
        const int r = rows[e];
        const int c = cols[e];
        const float v = vals[e];
        const float4 a = x4[(size_t)r * 32 + sub];
        const float4 b = x4[(size_t)c * 32 + sub];
        acc += v * (a.x * b.x + a.y * b.y + a.z * b.z + a.w * b.w);
    }
    #pragma unroll
    for (int m = 1; m < 64; m <<= 1)
        acc += __shfl_xor(acc, m);

    __shared__ float lds[4];
    const int lane = threadIdx.x & 63;
    const int wid  = threadIdx.x >> 6;
    if (lane == 0) lds[wid] = acc;
    __syncthreads();
    if (threadIdx.x == 0) {
        float s = 0.0f;
        const int nw = blockDim.x >> 6;
        for (int w = 0; w < nw; ++w) s += lds[w];
        partials[blockIdx.x] = s;
    }
}

__global__ __launch_bounds__(1024) void final_reduce_kernel(
    const float* __restrict__ partials, int n,
    float* __restrict__ out, float inv_nnz)
{
    float acc = 0.0f;
    for (int i = threadIdx.x; i < n; i += blockDim.x)
        acc += partials[i];
    #pragma unroll
    for (int m = 1; m < 64; m <<= 1)
        acc += __shfl_xor(acc, m);

    __shared__ float lds[16];
    const int lane = threadIdx.x & 63;
    const int wid  = threadIdx.x >> 6;
    if (lane == 0) lds[wid] = acc;
    __syncthreads();
    if (threadIdx.x == 0) {
        float s = 0.0f;
        const int nw = blockDim.x >> 6;
        for (int w = 0; w < nw; ++w) s += lds[w];
        out[0] = s * inv_nnz;
    }
}

extern "C" void kernel_launch(void* const* d_in, const int* in_sizes, int n_in,
                              void* d_out, int out_size, void* d_ws, size_t ws_size,
                              hipStream_t stream) {
    const float* x    = (const float*)d_in[0];
    const int*   rows = (const int*)d_in[1];
    const int*   cols = (const int*)d_in[2];
    const float* vals = (const float*)d_in[3];
    const int nnz = in_sizes[1];
    const int nfeat_total = in_sizes[0];          // N_NODES * 128
    const int n_nodes = nfeat_total / 128;
    const int nodes_per_oct = (n_nodes + 7) / 8;
    const size_t xh_bytes = (size_t)nfeat_total * sizeof(__half);

    const int grid = 2048;                        // multiple of 8
    const size_t need = xh_bytes + 256 + (size_t)grid * sizeof(float);

    if (ws_size >= need) {
        __half* xh = (__half*)d_ws;
        size_t poff = (xh_bytes + 255) & ~(size_t)255;
        float* partials = (float*)((char*)d_ws + poff);

        const int n4 = nfeat_total / 4;
        convert_f2h_kernel<<<2048, 256, 0, stream>>>(x, (h4pack*)d_ws, n4);

        edge_dot_oct_kernel<<<grid, 256, 0, stream>>>(
            xh, rows, cols, vals, partials, nnz, nodes_per_oct);
        final_reduce_kernel<<<1, 1024, 0, stream>>>(partials, grid, (float*)d_out,
                                                    1.0f / (float)nnz);
    } else {
        float* partials = (float*)d_ws;
        int g = grid;
        if ((size_t)g * sizeof(float) > ws_size) g = (int)(ws_size / sizeof(float));
        const int maxGroups = (nnz + 7) / 8;
        if (g > maxGroups) g = maxGroups;
        if (g < 1) g = 1;
        edge_dot_f_kernel<<<g, 256, 0, stream>>>(x, rows, cols, vals, partials, nnz);
        final_reduce_kernel<<<1, 1024, 0, stream>>>(partials, g, (float*)d_out,
                                                    1.0f / (float)nnz);
    }
}